// Round 3
// baseline (569.709 us; speedup 1.0000x reference)
//
#include <hip/hip_runtime.h>
#include <hip/hip_bf16.h>

// N=8192, D=1024, D_qk=D_v=256, scores *= sqrt(D_qk)=16 (folded into Q).
// convert_x (fp32->bf16 hi/lo) -> proj (MFMA GEMM, hi/lo 3-term) ->
// flash (BM=64, 4 waves, KV-split=8, global_load_lds staging, defer-max) -> combine.

typedef __attribute__((ext_vector_type(8))) short short8;   // 8 bf16 (MFMA frag)
typedef __attribute__((ext_vector_type(4))) float f32x4;    // MFMA acc frag
typedef __attribute__((ext_vector_type(4))) unsigned int u32x4;

#define MFMA16(a, b, c) __builtin_amdgcn_mfma_f32_16x16x32_bf16((a), (b), (c), 0, 0, 0)

__device__ __forceinline__ unsigned short f2bf(float f) {
    unsigned int u = __builtin_bit_cast(unsigned int, f);
    u += 0x7fffu + ((u >> 16) & 1u);   // RNE
    return (unsigned short)(u >> 16);
}
__device__ __forceinline__ float bf2f(unsigned short h) {
    unsigned int u = ((unsigned int)h) << 16;
    return __builtin_bit_cast(float, u);
}

// async global->LDS, 16B per lane; lds dest = wave-uniform base + lane*16
__device__ __forceinline__ void gl16(const unsigned short* g, unsigned short* l) {
    __builtin_amdgcn_global_load_lds(
        (const __attribute__((address_space(1))) unsigned int*)g,
        (__attribute__((address_space(3))) unsigned int*)l,
        16, 0, 0);
}

// ---------------- kernel 1: x fp32 -> xhi + xlo bf16 ----------------
__global__ void convert_x_kernel(const float* __restrict__ x,
                                 unsigned short* __restrict__ xhi,
                                 unsigned short* __restrict__ xlo) {
    int i = blockIdx.x * blockDim.x + threadIdx.x;   // 4 elements/thread
    float4 v = reinterpret_cast<const float4*>(x)[i];
    float f[4] = {v.x, v.y, v.z, v.w};
    ushort4 hi, lo;
    unsigned short th[4], tl[4];
#pragma unroll
    for (int j = 0; j < 4; ++j) {
        th[j] = f2bf(f[j]);
        tl[j] = f2bf(f[j] - bf2f(th[j]));
    }
    hi.x = th[0]; hi.y = th[1]; hi.z = th[2]; hi.w = th[3];
    lo.x = tl[0]; lo.y = tl[1]; lo.z = tl[2]; lo.w = tl[3];
    reinterpret_cast<ushort4*>(xhi)[i] = hi;
    reinterpret_cast<ushort4*>(xlo)[i] = lo;
}

// ---------------- kernel 2: projections ----------------
__launch_bounds__(256, 4)
__global__ void proj_kernel(const unsigned short* __restrict__ xhi,
                            const unsigned short* __restrict__ xlo,
                            const float* __restrict__ Wq, const float* __restrict__ Wk,
                            const float* __restrict__ Wv,
                            unsigned short* __restrict__ Qhi, unsigned short* __restrict__ Qlo,
                            unsigned short* __restrict__ Khi, unsigned short* __restrict__ Klo,
                            unsigned short* __restrict__ VT) {
    __shared__ __align__(16) unsigned short xh[64 * 32], xl[64 * 32];
    __shared__ __align__(16) unsigned short wh[64 * 32], wl[64 * 32];
    const int t = threadIdx.x;
    const int mtile = blockIdx.x;
    const int y = blockIdx.y;
    const int w = y >> 2, nt = y & 3;
    const int mb = mtile * 64, nb = nt * 64;
    const float* W = (w == 0) ? Wq : (w == 1) ? Wk : Wv;
    const int wid = t >> 6, lane = t & 63, lr = lane & 15, lg = lane >> 4;

    const f32x4 fzero = {0.f, 0.f, 0.f, 0.f};
    f32x4 acc[4];
#pragma unroll
    for (int i = 0; i < 4; ++i) acc[i] = fzero;

    for (int ks = 0; ks < 32; ++ks) {
        const int k0 = ks * 32;
        {   // stage x hi/lo tile [64][32]
            int row = t >> 2, cb = t & 3;
            int g = (mb + row) * 1024 + k0 + cb * 8;
            int idx = (row * 32 + cb * 8) ^ ((row & 7) << 3);
            *reinterpret_cast<u32x4*>(&xh[idx]) = *reinterpret_cast<const u32x4*>(xhi + g);
            *reinterpret_cast<u32x4*>(&xl[idx]) = *reinterpret_cast<const u32x4*>(xlo + g);
        }
#pragma unroll
        for (int p = 0; p < 2; ++p) {   // stage W tile fp32 -> hi/lo bf16
            int c = p * 256 + t;
            int row = c >> 3, fb = c & 7;
            float4 v = *reinterpret_cast<const float4*>(W + (nb + row) * 1024 + k0 + fb * 4);
            float ff[4] = {v.x, v.y, v.z, v.w};
            ushort4 hh, ll;
            unsigned short th[4], tl[4];
#pragma unroll
            for (int j = 0; j < 4; ++j) {
                th[j] = f2bf(ff[j]);
                tl[j] = f2bf(ff[j] - bf2f(th[j]));
            }
            hh.x = th[0]; hh.y = th[1]; hh.z = th[2]; hh.w = th[3];
            ll.x = tl[0]; ll.y = tl[1]; ll.z = tl[2]; ll.w = tl[3];
            int idx = (row * 32 + fb * 4) ^ ((row & 7) << 3);
            *reinterpret_cast<ushort4*>(&wh[idx]) = hh;
            *reinterpret_cast<ushort4*>(&wl[idx]) = ll;
        }
        __syncthreads();
        {
            int arow = wid * 16 + lr;
            int aidx = (arow * 32 + lg * 8) ^ ((arow & 7) << 3);
            short8 ah = *reinterpret_cast<const short8*>(&xh[aidx]);
            short8 al = *reinterpret_cast<const short8*>(&xl[aidx]);
#pragma unroll
            for (int ct = 0; ct < 4; ++ct) {
                int brow = ct * 16 + lr;
                int bidx = (brow * 32 + lg * 8) ^ ((brow & 7) << 3);
                short8 bh = *reinterpret_cast<const short8*>(&wh[bidx]);
                short8 bl = *reinterpret_cast<const short8*>(&wl[bidx]);
                acc[ct] = MFMA16(ah, bh, acc[ct]);
                acc[ct] = MFMA16(ah, bl, acc[ct]);
                acc[ct] = MFMA16(al, bh, acc[ct]);
            }
        }
        __syncthreads();
    }
    const int rbase = mb + wid * 16 + lg * 4;
#pragma unroll
    for (int ct = 0; ct < 4; ++ct) {
        int col = nb + ct * 16 + lr;
        if (w == 2) {   // V stored transposed
            ushort4 v4;
            v4.x = f2bf(acc[ct][0]); v4.y = f2bf(acc[ct][1]);
            v4.z = f2bf(acc[ct][2]); v4.w = f2bf(acc[ct][3]);
            *reinterpret_cast<ushort4*>(VT + (size_t)col * 8192 + rbase) = v4;
        } else {
            unsigned short* Hi = (w == 0) ? Qhi : Khi;
            unsigned short* Lo = (w == 0) ? Qlo : Klo;
            const float scale = (w == 0) ? 16.0f : 1.0f;
#pragma unroll
            for (int j = 0; j < 4; ++j) {
                float v = acc[ct][j] * scale;
                unsigned short h = f2bf(v);
                unsigned short lo = f2bf(v - bf2f(h));
                Hi[(size_t)(rbase + j) * 256 + col] = h;
                Lo[(size_t)(rbase + j) * 256 + col] = lo;
            }
        }
    }
}

// ---------------- kernel 3: flash attention ----------------
// BM=64 (4 waves x 16 rows), KVBLK=32, KV-split=8 (1024 kv each, split==XCD).
// LDS 52KB -> 3 blocks/CU. global_load_lds staging, involution swizzles.
__launch_bounds__(256, 3)
__global__ void flash_kernel(const unsigned short* __restrict__ Qhi,
                             const unsigned short* __restrict__ Qlo,
                             const unsigned short* __restrict__ Khi_g,
                             const unsigned short* __restrict__ Klo_g,
                             const unsigned short* __restrict__ VT,
                             unsigned short* __restrict__ Opart,
                             float* __restrict__ Mpart, float* __restrict__ Lpart) {
    __shared__ __align__(16) unsigned short Kh[32 * 256], Kl[32 * 256];
    __shared__ __align__(16) unsigned short Vt[256 * 32];
    __shared__ __align__(16) unsigned short Pb[4 * 16 * 32];
    const int t = threadIdx.x;
    const int split = blockIdx.x & 7;          // == XCD (chunked): KV slice L2-resident
    const int mtile = blockIdx.x >> 3;
    const int mb = mtile * 64;
    const int kv0 = split * 1024;
    const int wid = t >> 6, lane = t & 63, lr = lane & 15, lg = lane >> 4;

    // Q fragments in registers: row=lane&15, k=(lane>>4)*8+j, 8 K-steps
    const int qrow = mb + wid * 16 + lr;
    short8 qh[8], ql[8];
#pragma unroll
    for (int ko = 0; ko < 8; ++ko) {
        int g = qrow * 256 + ko * 32 + lg * 8;
        qh[ko] = *reinterpret_cast<const short8*>(Qhi + g);
        ql[ko] = *reinterpret_cast<const short8*>(Qlo + g);
    }

    // --- precomputed staging offsets (per-lane, u16 units) ---
    int khoff[4], vtoff[4], kc[4];
#pragma unroll
    for (int i = 0; i < 4; ++i) {
        int c = wid * 4 + i;
        kc[i] = c * 512;
        int krow = c * 2 + (lane >> 5), ksl = lane & 31;
        khoff[i] = krow * 256 + ((ksl ^ (krow & 7)) << 3);
        int vrow = c * 16 + (lane >> 2), vl = lane & 3;
        vtoff[i] = vrow * 8192 + ((vl ^ (vrow & 3)) << 3);
    }

    const f32x4 fzero = {0.f, 0.f, 0.f, 0.f};
    f32x4 acc[16];
#pragma unroll
    for (int i = 0; i < 16; ++i) acc[i] = fzero;
    float m[4], lp[4];
#pragma unroll
    for (int j = 0; j < 4; ++j) { m[j] = -__builtin_inff(); lp[j] = 0.f; }
    unsigned short* Pw = Pb + wid * 512;
    const int xr7 = lr & 7, xr3 = lr & 3, xf = (lr >> 1) & 3;

    for (int it = 0; it < 32; ++it) {
        const int kvb = kv0 + it * 32;
        const int kb = kvb << 8;   // kvb*256
        // ---- async stage K hi/lo [32][256] + V^T [256][32] ----
#pragma unroll
        for (int i = 0; i < 4; ++i) {
            gl16(Khi_g + kb + khoff[i], (unsigned short*)Kh + kc[i]);
            gl16(Klo_g + kb + khoff[i], (unsigned short*)Kl + kc[i]);
            gl16(VT + kvb + vtoff[i], (unsigned short*)Vt + kc[i]);
        }
        asm volatile("s_waitcnt vmcnt(0)" ::: "memory");
        __syncthreads();
        // ---- S = Q K^T : 16 q-rows x 32 kv-cols per wave, 3-term hi/lo ----
        f32x4 s0 = fzero, s1 = fzero;
#pragma unroll
        for (int ko = 0; ko < 8; ++ko) {
            int sl = (((ko * 4 + lg) ^ xr7) << 3);
            int b0 = lr * 256 + sl;
            int b1 = b0 + 4096;
            short8 bh0 = *reinterpret_cast<const short8*>(&Kh[b0]);
            short8 bl0 = *reinterpret_cast<const short8*>(&Kl[b0]);
            short8 bh1 = *reinterpret_cast<const short8*>(&Kh[b1]);
            short8 bl1 = *reinterpret_cast<const short8*>(&Kl[b1]);
            s0 = MFMA16(qh[ko], bh0, s0);
            s1 = MFMA16(qh[ko], bh1, s1);
            s0 = MFMA16(qh[ko], bl0, s0);
            s1 = MFMA16(qh[ko], bl1, s1);
            s0 = MFMA16(ql[ko], bh0, s0);
            s1 = MFMA16(ql[ko], bh1, s1);
        }
        // ---- online softmax with defer-max (THR=4), per-lane l accumulation ----
        float mx[4];
#pragma unroll
        for (int j = 0; j < 4; ++j) {
            float v = fmaxf(s0[j], s1[j]);
            v = fmaxf(v, __shfl_xor(v, 1));
            v = fmaxf(v, __shfl_xor(v, 2));
            v = fmaxf(v, __shfl_xor(v, 4));
            v = fmaxf(v, __shfl_xor(v, 8));
            mx[j] = v;
        }
        float g = fmaxf(fmaxf(mx[0] - m[0], mx[1] - m[1]),
                        fmaxf(mx[2] - m[2], mx[3] - m[3]));
        if (!__all(g <= 4.0f)) {           // wave-uniform rescale (rare after warmup)
#pragma unroll
            for (int j = 0; j < 4; ++j) {
                float nm = fmaxf(m[j], mx[j]);
                float sc = __expf(m[j] - nm);
                m[j] = nm;
                lp[j] *= sc;
#pragma unroll
                for (int dt = 0; dt < 16; ++dt) acc[dt][j] *= sc;
            }
        }
#pragma unroll
        for (int j = 0; j < 4; ++j) {
            float p0 = __expf(s0[j] - m[j]);   // bounded by e^4
            float p1 = __expf(s1[j] - m[j]);
            unsigned short pb0 = f2bf(p0), pb1 = f2bf(p1);
            lp[j] += bf2f(pb0) + bf2f(pb1);    // l from rounded p: common-mode cancels
            int prow = lg * 4 + j;
            int f = (prow >> 1) & 3;
            Pw[prow * 32 + (((lr >> 3) ^ f) << 3) + (lr & 7)] = pb0;
            Pw[prow * 32 + ((((lr >> 3) + 2) ^ f) << 3) + (lr & 7)] = pb1;
        }
        asm volatile("s_waitcnt lgkmcnt(0)" ::: "memory");   // wave-local P w->r
        short8 pa = *reinterpret_cast<const short8*>(&Pw[lr * 32 + ((lg ^ xf) << 3)]);
        // ---- O += P V ----
#pragma unroll
        for (int dt = 0; dt < 16; ++dt) {
            int vidx = (dt * 16 + lr) * 32 + ((lg ^ xr3) << 3);
            short8 bv = *reinterpret_cast<const short8*>(&Vt[vidx]);
            acc[dt] = MFMA16(pa, bv, acc[dt]);
        }
        __syncthreads();
    }
    // ---- epilogue: l = reduce(lp); store bf16 O + (m, l) ----
    unsigned short* Ob = Opart + (size_t)split * 8192 * 256;
    const int rb = mb + wid * 16 + lg * 4;
#pragma unroll
    for (int j = 0; j < 4; ++j) {
        float s = lp[j];
        s += __shfl_xor(s, 1);
        s += __shfl_xor(s, 2);
        s += __shfl_xor(s, 4);
        s += __shfl_xor(s, 8);
#pragma unroll
        for (int dt = 0; dt < 16; ++dt) {
            Ob[(size_t)(rb + j) * 256 + dt * 16 + lr] = f2bf(acc[dt][j]);
        }
        if (lr == 0) {
            Mpart[split * 8192 + rb + j] = m[j];
            Lpart[split * 8192 + rb + j] = s;
        }
    }
}

// ---------------- kernel 4: combine 8 KV-split partials ----------------
__global__ void combine_kernel(const unsigned short* __restrict__ Opart,
                               const float* __restrict__ Mpart,
                               const float* __restrict__ Lpart,
                               float* __restrict__ out) {
    const int row = blockIdx.x;
    const int d = threadIdx.x;
    float mm = -__builtin_inff();
#pragma unroll
    for (int s = 0; s < 8; ++s) mm = fmaxf(mm, Mpart[s * 8192 + row]);
    float num = 0.f, den = 0.f;
#pragma unroll
    for (int s = 0; s < 8; ++s) {
        float w = __expf(Mpart[s * 8192 + row] - mm);
        den += w * Lpart[s * 8192 + row];
        num += w * bf2f(Opart[((size_t)s * 8192 + row) * 256 + d]);
    }
    out[(size_t)row * 256 + d] = num / den;
}

extern "C" void kernel_launch(void* const* d_in, const int* in_sizes, int n_in,
                              void* d_out, int out_size, void* d_ws, size_t ws_size,
                              hipStream_t stream) {
    const float* x  = (const float*)d_in[0];
    const float* Wq = (const float*)d_in[1];
    const float* Wk = (const float*)d_in[2];
    const float* Wv = (const float*)d_in[3];
    float* out = (float*)d_out;

    char* ws = (char*)d_ws;
    const size_t SZ_QK = (size_t)8192 * 256 * 2;     // 4 MiB per bf16 array
    unsigned short* Qhi = (unsigned short*)(ws + 0 * SZ_QK);
    unsigned short* Qlo = (unsigned short*)(ws + 1 * SZ_QK);
    unsigned short* Khi = (unsigned short*)(ws + 2 * SZ_QK);
    unsigned short* Klo = (unsigned short*)(ws + 3 * SZ_QK);
    unsigned short* VT  = (unsigned short*)(ws + 4 * SZ_QK);
    float* Mpart = (float*)(ws + 5 * SZ_QK);                    // 8*8192*4 = 256KB
    float* Lpart = (float*)(ws + 5 * SZ_QK + 262144);           // 256KB
    char* uA = ws + 5 * SZ_QK + 524288;              // union region:
    unsigned short* xhi = (unsigned short*)uA;       //   phase A: xhi+xlo (32 MiB)
    unsigned short* xlo = (unsigned short*)(uA + (size_t)8192 * 1024 * 2);
    unsigned short* Opart = (unsigned short*)uA;     //   phase B: Opart bf16 (32 MiB)

    convert_x_kernel<<<8192, 256, 0, stream>>>(x, xhi, xlo);
    proj_kernel<<<dim3(128, 12), 256, 0, stream>>>(xhi, xlo, Wq, Wk, Wv,
                                                   Qhi, Qlo, Khi, Klo, VT);
    flash_kernel<<<1024, 256, 0, stream>>>(Qhi, Qlo, Khi, Klo, VT, Opart, Mpart, Lpart);
    combine_kernel<<<8192, 256, 0, stream>>>(Opart, Mpart, Lpart, out);
}

// Round 5
// 339.254 us; speedup vs baseline: 1.6793x; 1.6793x over previous
//
#include <hip/hip_runtime.h>
#include <hip/hip_bf16.h>

// N=8192, D=1024, D_qk=D_v=256, scores *= sqrt(D_qk)=16 (folded into Q).
// convert_x (fp32->bf16 hi/lo) -> proj (MFMA GEMM, hi/lo 3-term) ->
// flash (BM=64, 4 waves, KV-split=4, 512 blocks = 2/CU all-resident lockstep,
//        global_load_lds staging, defer-max, setprio) -> combine.

typedef __attribute__((ext_vector_type(8))) short short8;   // 8 bf16 (MFMA frag)
typedef __attribute__((ext_vector_type(4))) float f32x4;    // MFMA acc frag
typedef __attribute__((ext_vector_type(4))) unsigned int u32x4;

#define MFMA16(a, b, c) __builtin_amdgcn_mfma_f32_16x16x32_bf16((a), (b), (c), 0, 0, 0)

__device__ __forceinline__ unsigned short f2bf(float f) {
    unsigned int u = __builtin_bit_cast(unsigned int, f);
    u += 0x7fffu + ((u >> 16) & 1u);   // RNE
    return (unsigned short)(u >> 16);
}
__device__ __forceinline__ float bf2f(unsigned short h) {
    unsigned int u = ((unsigned int)h) << 16;
    return __builtin_bit_cast(float, u);
}

// async global->LDS, 16B per lane; lds dest = wave-uniform base + lane*16
__device__ __forceinline__ void gl16(const unsigned short* g, unsigned short* l) {
    __builtin_amdgcn_global_load_lds(
        (const __attribute__((address_space(1))) unsigned int*)g,
        (__attribute__((address_space(3))) unsigned int*)l,
        16, 0, 0);
}

// ---------------- kernel 1: x fp32 -> xhi + xlo bf16 ----------------
__global__ void convert_x_kernel(const float* __restrict__ x,
                                 unsigned short* __restrict__ xhi,
                                 unsigned short* __restrict__ xlo) {
    int i = blockIdx.x * blockDim.x + threadIdx.x;   // 4 elements/thread
    float4 v = reinterpret_cast<const float4*>(x)[i];
    float f[4] = {v.x, v.y, v.z, v.w};
    ushort4 hi, lo;
    unsigned short th[4], tl[4];
#pragma unroll
    for (int j = 0; j < 4; ++j) {
        th[j] = f2bf(f[j]);
        tl[j] = f2bf(f[j] - bf2f(th[j]));
    }
    hi.x = th[0]; hi.y = th[1]; hi.z = th[2]; hi.w = th[3];
    lo.x = tl[0]; lo.y = tl[1]; lo.z = tl[2]; lo.w = tl[3];
    reinterpret_cast<ushort4*>(xhi)[i] = hi;
    reinterpret_cast<ushort4*>(xlo)[i] = lo;
}

// ---------------- kernel 2: projections ----------------
__launch_bounds__(256, 4)
__global__ void proj_kernel(const unsigned short* __restrict__ xhi,
                            const unsigned short* __restrict__ xlo,
                            const float* __restrict__ Wq, const float* __restrict__ Wk,
                            const float* __restrict__ Wv,
                            unsigned short* __restrict__ Qhi, unsigned short* __restrict__ Qlo,
                            unsigned short* __restrict__ Khi, unsigned short* __restrict__ Klo,
                            unsigned short* __restrict__ VT) {
    __shared__ __align__(16) unsigned short xh[64 * 32], xl[64 * 32];
    __shared__ __align__(16) unsigned short wh[64 * 32], wl[64 * 32];
    const int t = threadIdx.x;
    const int mtile = blockIdx.x;
    const int y = blockIdx.y;
    const int w = y >> 2, nt = y & 3;
    const int mb = mtile * 64, nb = nt * 64;
    const float* W = (w == 0) ? Wq : (w == 1) ? Wk : Wv;
    const int wid = t >> 6, lane = t & 63, lr = lane & 15, lg = lane >> 4;

    const f32x4 fzero = {0.f, 0.f, 0.f, 0.f};
    f32x4 acc[4];
#pragma unroll
    for (int i = 0; i < 4; ++i) acc[i] = fzero;

    for (int ks = 0; ks < 32; ++ks) {
        const int k0 = ks * 32;
        {   // stage x hi/lo tile [64][32]
            int row = t >> 2, cb = t & 3;
            int g = (mb + row) * 1024 + k0 + cb * 8;
            int idx = (row * 32 + cb * 8) ^ ((row & 7) << 3);
            *reinterpret_cast<u32x4*>(&xh[idx]) = *reinterpret_cast<const u32x4*>(xhi + g);
            *reinterpret_cast<u32x4*>(&xl[idx]) = *reinterpret_cast<const u32x4*>(xlo + g);
        }
#pragma unroll
        for (int p = 0; p < 2; ++p) {   // stage W tile fp32 -> hi/lo bf16
            int c = p * 256 + t;
            int row = c >> 3, fb = c & 7;
            float4 v = *reinterpret_cast<const float4*>(W + (nb + row) * 1024 + k0 + fb * 4);
            float ff[4] = {v.x, v.y, v.z, v.w};
            ushort4 hh, ll;
            unsigned short th[4], tl[4];
#pragma unroll
            for (int j = 0; j < 4; ++j) {
                th[j] = f2bf(ff[j]);
                tl[j] = f2bf(ff[j] - bf2f(th[j]));
            }
            hh.x = th[0]; hh.y = th[1]; hh.z = th[2]; hh.w = th[3];
            ll.x = tl[0]; ll.y = tl[1]; ll.z = tl[2]; ll.w = tl[3];
            int idx = (row * 32 + fb * 4) ^ ((row & 7) << 3);
            *reinterpret_cast<ushort4*>(&wh[idx]) = hh;
            *reinterpret_cast<ushort4*>(&wl[idx]) = ll;
        }
        __syncthreads();
        {
            int arow = wid * 16 + lr;
            int aidx = (arow * 32 + lg * 8) ^ ((arow & 7) << 3);
            short8 ah = *reinterpret_cast<const short8*>(&xh[aidx]);
            short8 al = *reinterpret_cast<const short8*>(&xl[aidx]);
#pragma unroll
            for (int ct = 0; ct < 4; ++ct) {
                int brow = ct * 16 + lr;
                int bidx = (brow * 32 + lg * 8) ^ ((brow & 7) << 3);
                short8 bh = *reinterpret_cast<const short8*>(&wh[bidx]);
                short8 bl = *reinterpret_cast<const short8*>(&wl[bidx]);
                acc[ct] = MFMA16(ah, bh, acc[ct]);
                acc[ct] = MFMA16(ah, bl, acc[ct]);
                acc[ct] = MFMA16(al, bh, acc[ct]);
            }
        }
        __syncthreads();
    }
    const int rbase = mb + wid * 16 + lg * 4;
#pragma unroll
    for (int ct = 0; ct < 4; ++ct) {
        int col = nb + ct * 16 + lr;
        if (w == 2) {   // V stored transposed
            ushort4 v4;
            v4.x = f2bf(acc[ct][0]); v4.y = f2bf(acc[ct][1]);
            v4.z = f2bf(acc[ct][2]); v4.w = f2bf(acc[ct][3]);
            *reinterpret_cast<ushort4*>(VT + (size_t)col * 8192 + rbase) = v4;
        } else {
            unsigned short* Hi = (w == 0) ? Qhi : Khi;
            unsigned short* Lo = (w == 0) ? Qlo : Klo;
            const float scale = (w == 0) ? 16.0f : 1.0f;
#pragma unroll
            for (int j = 0; j < 4; ++j) {
                float v = acc[ct][j] * scale;
                unsigned short h = f2bf(v);
                unsigned short lo = f2bf(v - bf2f(h));
                Hi[(size_t)(rbase + j) * 256 + col] = h;
                Lo[(size_t)(rbase + j) * 256 + col] = lo;
            }
        }
    }
}

// ---------------- kernel 3: flash attention ----------------
// BM=64 (4 waves x 16 rows), KVBLK=32, KV-split=4.
// 512 blocks = exactly 2/CU, ALL resident from t=0 (lockstep -> L2-resident KV).
// XCD pairs {2s,2s+1} own split s (3MB slice per XCD L2).
__launch_bounds__(256, 2)
__global__ void flash_kernel(const unsigned short* __restrict__ Qhi,
                             const unsigned short* __restrict__ Qlo,
                             const unsigned short* __restrict__ Khi_g,
                             const unsigned short* __restrict__ Klo_g,
                             const unsigned short* __restrict__ VT,
                             unsigned short* __restrict__ Opart,
                             float* __restrict__ Mpart, float* __restrict__ Lpart) {
    __shared__ __align__(16) unsigned short Kh[32 * 256], Kl[32 * 256];
    __shared__ __align__(16) unsigned short Vt[256 * 32];
    __shared__ __align__(16) unsigned short Pb[4 * 16 * 32];
    const int t = threadIdx.x;
    // HW maps bid%8 -> XCD. work = xcd*64 + bid/8; split = work>>7 (XCD pair),
    // mtile = work&127. All blocks of one XCD share one KV slice.
    const int bid = blockIdx.x;
    const int work = (bid & 7) * 64 + (bid >> 3);
    const int split = work >> 7, mtile = work & 127;
    const int mb = mtile * 64;
    const int kv0 = split * 2048;
    const int wid = t >> 6, lane = t & 63, lr = lane & 15, lg = lane >> 4;

    // Q fragments in registers: row=lane&15, k=(lane>>4)*8+j, 8 K-steps
    const int qrow = mb + wid * 16 + lr;
    short8 qh[8], ql[8];
#pragma unroll
    for (int ko = 0; ko < 8; ++ko) {
        int g = qrow * 256 + ko * 32 + lg * 8;
        qh[ko] = *reinterpret_cast<const short8*>(Qhi + g);
        ql[ko] = *reinterpret_cast<const short8*>(Qlo + g);
    }

    // --- precomputed staging offsets (per-lane, u16 units) ---
    int khoff[4], vtoff[4], kc[4];
#pragma unroll
    for (int i = 0; i < 4; ++i) {
        int c = wid * 4 + i;
        kc[i] = c * 512;
        int krow = c * 2 + (lane >> 5), ksl = lane & 31;
        khoff[i] = krow * 256 + ((ksl ^ (krow & 7)) << 3);
        int vrow = c * 16 + (lane >> 2), vl = lane & 3;
        vtoff[i] = vrow * 8192 + ((vl ^ (vrow & 3)) << 3);
    }

    const f32x4 fzero = {0.f, 0.f, 0.f, 0.f};
    f32x4 acc[16];
#pragma unroll
    for (int i = 0; i < 16; ++i) acc[i] = fzero;
    float m[4], lp[4];
#pragma unroll
    for (int j = 0; j < 4; ++j) { m[j] = -__builtin_inff(); lp[j] = 0.f; }
    unsigned short* Pw = Pb + wid * 512;
    const int xr7 = lr & 7, xr3 = lr & 3, xf = (lr >> 1) & 3;

    for (int it = 0; it < 64; ++it) {
        const int kvb = kv0 + it * 32;
        const int kb = kvb << 8;   // kvb*256
        // ---- async stage K hi/lo [32][256] + V^T [256][32] ----
#pragma unroll
        for (int i = 0; i < 4; ++i) {
            gl16(Khi_g + kb + khoff[i], (unsigned short*)Kh + kc[i]);
            gl16(Klo_g + kb + khoff[i], (unsigned short*)Kl + kc[i]);
            gl16(VT + kvb + vtoff[i], (unsigned short*)Vt + kc[i]);
        }
        asm volatile("s_waitcnt vmcnt(0)" ::: "memory");
        __syncthreads();
        // ---- S = Q K^T : 16 q-rows x 32 kv-cols per wave, 3-term hi/lo ----
        f32x4 s0 = fzero, s1 = fzero;
        __builtin_amdgcn_s_setprio(1);
#pragma unroll
        for (int ko = 0; ko < 8; ++ko) {
            int sl = (((ko * 4 + lg) ^ xr7) << 3);
            int b0 = lr * 256 + sl;
            int b1 = b0 + 4096;
            short8 bh0 = *reinterpret_cast<const short8*>(&Kh[b0]);
            short8 bl0 = *reinterpret_cast<const short8*>(&Kl[b0]);
            short8 bh1 = *reinterpret_cast<const short8*>(&Kh[b1]);
            short8 bl1 = *reinterpret_cast<const short8*>(&Kl[b1]);
            s0 = MFMA16(qh[ko], bh0, s0);
            s1 = MFMA16(qh[ko], bh1, s1);
            s0 = MFMA16(qh[ko], bl0, s0);
            s1 = MFMA16(qh[ko], bl1, s1);
            s0 = MFMA16(ql[ko], bh0, s0);
            s1 = MFMA16(ql[ko], bh1, s1);
        }
        __builtin_amdgcn_s_setprio(0);
        // ---- online softmax with defer-max (THR=4), per-lane l accumulation ----
        float mx[4];
#pragma unroll
        for (int j = 0; j < 4; ++j) {
            float v = fmaxf(s0[j], s1[j]);
            v = fmaxf(v, __shfl_xor(v, 1));
            v = fmaxf(v, __shfl_xor(v, 2));
            v = fmaxf(v, __shfl_xor(v, 4));
            v = fmaxf(v, __shfl_xor(v, 8));
            mx[j] = v;
        }
        float g = fmaxf(fmaxf(mx[0] - m[0], mx[1] - m[1]),
                        fmaxf(mx[2] - m[2], mx[3] - m[3]));
        if (!__all(g <= 4.0f)) {           // wave-uniform rescale (rare after warmup)
#pragma unroll
            for (int j = 0; j < 4; ++j) {
                float nm = fmaxf(m[j], mx[j]);
                float sc = __expf(m[j] - nm);
                m[j] = nm;
                lp[j] *= sc;
#pragma unroll
                for (int dt = 0; dt < 16; ++dt) acc[dt][j] *= sc;
            }
        }
#pragma unroll
        for (int j = 0; j < 4; ++j) {
            float p0 = __expf(s0[j] - m[j]);   // bounded by e^4
            float p1 = __expf(s1[j] - m[j]);
            unsigned short pb0 = f2bf(p0), pb1 = f2bf(p1);
            lp[j] += bf2f(pb0) + bf2f(pb1);    // l from rounded p: common-mode cancels
            int prow = lg * 4 + j;
            int f = (prow >> 1) & 3;
            Pw[prow * 32 + (((lr >> 3) ^ f) << 3) + (lr & 7)] = pb0;
            Pw[prow * 32 + ((((lr >> 3) + 2) ^ f) << 3) + (lr & 7)] = pb1;
        }
        asm volatile("s_waitcnt lgkmcnt(0)" ::: "memory");   // wave-local P w->r
        short8 pa = *reinterpret_cast<const short8*>(&Pw[lr * 32 + ((lg ^ xf) << 3)]);
        // ---- O += P V ----
        __builtin_amdgcn_s_setprio(1);
#pragma unroll
        for (int dt = 0; dt < 16; ++dt) {
            int vidx = (dt * 16 + lr) * 32 + ((lg ^ xr3) << 3);
            short8 bv = *reinterpret_cast<const short8*>(&Vt[vidx]);
            acc[dt] = MFMA16(pa, bv, acc[dt]);
        }
        __builtin_amdgcn_s_setprio(0);
        __syncthreads();
    }
    // ---- epilogue: l = reduce(lp); store bf16 O + (m, l) ----
    unsigned short* Ob = Opart + (size_t)split * 8192 * 256;
    const int rb = mb + wid * 16 + lg * 4;
#pragma unroll
    for (int j = 0; j < 4; ++j) {
        float s = lp[j];
        s += __shfl_xor(s, 1);
        s += __shfl_xor(s, 2);
        s += __shfl_xor(s, 4);
        s += __shfl_xor(s, 8);
#pragma unroll
        for (int dt = 0; dt < 16; ++dt) {
            Ob[(size_t)(rb + j) * 256 + dt * 16 + lr] = f2bf(acc[dt][j]);
        }
        if (lr == 0) {
            Mpart[split * 8192 + rb + j] = m[j];
            Lpart[split * 8192 + rb + j] = s;
        }
    }
}

// ---------------- kernel 4: combine 4 KV-split partials ----------------
__global__ void combine_kernel(const unsigned short* __restrict__ Opart,
                               const float* __restrict__ Mpart,
                               const float* __restrict__ Lpart,
                               float* __restrict__ out) {
    const int row = blockIdx.x;
    const int d = threadIdx.x;
    float mm = -__builtin_inff();
#pragma unroll
    for (int s = 0; s < 4; ++s) mm = fmaxf(mm, Mpart[s * 8192 + row]);
    float num = 0.f, den = 0.f;
#pragma unroll
    for (int s = 0; s < 4; ++s) {
        float w = __expf(Mpart[s * 8192 + row] - mm);
        den += w * Lpart[s * 8192 + row];
        num += w * bf2f(Opart[((size_t)s * 8192 + row) * 256 + d]);
    }
    out[(size_t)row * 256 + d] = num / den;
}

extern "C" void kernel_launch(void* const* d_in, const int* in_sizes, int n_in,
                              void* d_out, int out_size, void* d_ws, size_t ws_size,
                              hipStream_t stream) {
    const float* x  = (const float*)d_in[0];
    const float* Wq = (const float*)d_in[1];
    const float* Wk = (const float*)d_in[2];
    const float* Wv = (const float*)d_in[3];
    float* out = (float*)d_out;

    char* ws = (char*)d_ws;
    const size_t SZ_QK = (size_t)8192 * 256 * 2;     // 4 MiB per bf16 array
    unsigned short* Qhi = (unsigned short*)(ws + 0 * SZ_QK);
    unsigned short* Qlo = (unsigned short*)(ws + 1 * SZ_QK);
    unsigned short* Khi = (unsigned short*)(ws + 2 * SZ_QK);
    unsigned short* Klo = (unsigned short*)(ws + 3 * SZ_QK);
    unsigned short* VT  = (unsigned short*)(ws + 4 * SZ_QK);
    float* Mpart = (float*)(ws + 5 * SZ_QK);                    // 4*8192*4 = 128KB
    float* Lpart = (float*)(ws + 5 * SZ_QK + 131072);           // 128KB
    char* uA = ws + 5 * SZ_QK + 262144;              // union region:
    unsigned short* xhi = (unsigned short*)uA;       //   phase A: xhi+xlo (32 MiB)
    unsigned short* xlo = (unsigned short*)(uA + (size_t)8192 * 1024 * 2);
    unsigned short* Opart = (unsigned short*)uA;     //   phase B: Opart bf16 (16 MiB)

    convert_x_kernel<<<8192, 256, 0, stream>>>(x, xhi, xlo);
    proj_kernel<<<dim3(128, 12), 256, 0, stream>>>(xhi, xlo, Wq, Wk, Wv,
                                                   Qhi, Qlo, Khi, Klo, VT);
    flash_kernel<<<512, 256, 0, stream>>>(Qhi, Qlo, Khi, Klo, VT, Opart, Mpart, Lpart);
    combine_kernel<<<8192, 256, 0, stream>>>(Opart, Mpart, Lpart, out);
}

// Round 7
// 324.750 us; speedup vs baseline: 1.7543x; 1.0447x over previous
//
#include <hip/hip_runtime.h>
#include <hip/hip_bf16.h>

// N=8192, D=1024, D_qk=D_v=256, scores *= sqrt(D_qk)=16 (folded into Q).
// convert_x + convert_w (fp32->bf16 hi/lo) -> proj (gl16-staged MFMA, K-step 64)
// -> flash (swapped QK^T, in-register P butterfly, no P-LDS) -> combine.

typedef __attribute__((ext_vector_type(8))) short short8;   // 8 bf16 (MFMA frag)
typedef __attribute__((ext_vector_type(4))) float f32x4;    // MFMA acc frag
typedef __attribute__((ext_vector_type(4))) unsigned int u32x4;

#define MFMA16(a, b, c) __builtin_amdgcn_mfma_f32_16x16x32_bf16((a), (b), (c), 0, 0, 0)

__device__ __forceinline__ unsigned short f2bf(float f) {
    unsigned int u = __builtin_bit_cast(unsigned int, f);
    u += 0x7fffu + ((u >> 16) & 1u);   // RNE
    return (unsigned short)(u >> 16);
}
__device__ __forceinline__ float bf2f(unsigned short h) {
    unsigned int u = ((unsigned int)h) << 16;
    return __builtin_bit_cast(float, u);
}
// pack two f32 -> two bf16 in one u32 (lo = a, hi = b)
__device__ __forceinline__ unsigned int cvtpk(float a, float b) {
    unsigned int r;
    asm("v_cvt_pk_bf16_f32 %0, %1, %2" : "=v"(r) : "v"(a), "v"(b));
    return r;
}
// async global->LDS, 16B per lane; lds dest = wave-uniform base + lane*16
__device__ __forceinline__ void gl16(const unsigned short* g, unsigned short* l) {
    __builtin_amdgcn_global_load_lds(
        (const __attribute__((address_space(1))) unsigned int*)g,
        (__attribute__((address_space(3))) unsigned int*)l,
        16, 0, 0);
}

// ---------------- kernel 1a: x fp32 -> xhi + xlo bf16 ----------------
__global__ void convert_x_kernel(const float* __restrict__ x,
                                 unsigned short* __restrict__ xhi,
                                 unsigned short* __restrict__ xlo) {
    int i = blockIdx.x * blockDim.x + threadIdx.x;   // 4 elements/thread
    float4 v = reinterpret_cast<const float4*>(x)[i];
    float f[4] = {v.x, v.y, v.z, v.w};
    ushort4 hi, lo;
    unsigned short th[4], tl[4];
#pragma unroll
    for (int j = 0; j < 4; ++j) {
        th[j] = f2bf(f[j]);
        tl[j] = f2bf(f[j] - bf2f(th[j]));
    }
    hi.x = th[0]; hi.y = th[1]; hi.z = th[2]; hi.w = th[3];
    lo.x = tl[0]; lo.y = tl[1]; lo.z = tl[2]; lo.w = tl[3];
    reinterpret_cast<ushort4*>(xhi)[i] = hi;
    reinterpret_cast<ushort4*>(xlo)[i] = lo;
}

// ---------------- kernel 1b: W fp32 -> Whi + Wlo bf16 (once, not 128x) -----
__global__ void convert_w_kernel(const float* __restrict__ Wq,
                                 const float* __restrict__ Wk,
                                 const float* __restrict__ Wv,
                                 unsigned short* __restrict__ Whi,
                                 unsigned short* __restrict__ Wlo) {
    const float* W = (blockIdx.y == 0) ? Wq : (blockIdx.y == 1) ? Wk : Wv;
    int i = blockIdx.x * blockDim.x + threadIdx.x;   // 4 elements/thread
    float4 v = reinterpret_cast<const float4*>(W)[i];
    float f[4] = {v.x, v.y, v.z, v.w};
    ushort4 hi, lo;
    unsigned short th[4], tl[4];
#pragma unroll
    for (int j = 0; j < 4; ++j) {
        th[j] = f2bf(f[j]);
        tl[j] = f2bf(f[j] - bf2f(th[j]));
    }
    hi.x = th[0]; hi.y = th[1]; hi.z = th[2]; hi.w = th[3];
    lo.x = tl[0]; lo.y = tl[1]; lo.z = tl[2]; lo.w = tl[3];
    size_t off = (size_t)blockIdx.y * 65536 + i;   // in ushort4 units: 262144/4
    reinterpret_cast<ushort4*>(Whi)[off] = hi;
    reinterpret_cast<ushort4*>(Wlo)[off] = lo;
}

// ---------------- kernel 2: projections ----------------
// 64x64 tile, K-step 64, all-bf16 gl16 staging, 3-term hi/lo MFMA.
// LDS swizzle: [64][64] u16 tiles, storage idx = row*64 + (c ^ (row&7))*8.
__launch_bounds__(256, 4)
__global__ void proj_kernel(const unsigned short* __restrict__ xhi,
                            const unsigned short* __restrict__ xlo,
                            const unsigned short* __restrict__ Whi,
                            const unsigned short* __restrict__ Wlo,
                            unsigned short* __restrict__ Qhi, unsigned short* __restrict__ Qlo,
                            unsigned short* __restrict__ Khi, unsigned short* __restrict__ Klo,
                            unsigned short* __restrict__ VT) {
    __shared__ __align__(16) unsigned short xh[64 * 64], xl[64 * 64];
    __shared__ __align__(16) unsigned short wh[64 * 64], wl[64 * 64];
    const int t = threadIdx.x;
    const int mtile = blockIdx.x;
    const int y = blockIdx.y;
    const int w = y >> 2, nt = y & 3;
    const int mb = mtile * 64, nb = nt * 64;
    const unsigned short* WhiW = Whi + (size_t)w * 262144;
    const unsigned short* WloW = Wlo + (size_t)w * 262144;
    const int wid = t >> 6, lane = t & 63, lr = lane & 15, lg = lane >> 4;

    // staging: linear slot s -> content (row = s>>3, c = (s&7)^(row&7))
    int soff[2], ldst[2];
#pragma unroll
    for (int i = 0; i < 2; ++i) {
        int s = t + i * 256;
        int row = s >> 3, c = (s & 7) ^ (row & 7);
        soff[i] = row * 1024 + c * 8;   // u16 offset within matrix (row-major, ld=1024)
        ldst[i] = s * 8;                // u16 offset in LDS
    }

    const f32x4 fzero = {0.f, 0.f, 0.f, 0.f};
    f32x4 acc[4];
#pragma unroll
    for (int i = 0; i < 4; ++i) acc[i] = fzero;

    for (int ks = 0; ks < 16; ++ks) {
        const int k0 = ks * 64;
#pragma unroll
        for (int i = 0; i < 2; ++i) {
            gl16(xhi + (size_t)mb * 1024 + k0 + soff[i], xh + ldst[i]);
            gl16(xlo + (size_t)mb * 1024 + k0 + soff[i], xl + ldst[i]);
            gl16(WhiW + (size_t)nb * 1024 + k0 + soff[i], wh + ldst[i]);
            gl16(WloW + (size_t)nb * 1024 + k0 + soff[i], wl + ldst[i]);
        }
        asm volatile("s_waitcnt vmcnt(0)" ::: "memory");
        __syncthreads();
        {
            const int arow = wid * 16 + lr;
            short8 ah[2], al[2];
#pragma unroll
            for (int ko = 0; ko < 2; ++ko) {
                int aidx = arow * 64 + (((ko * 4 + lg) ^ (arow & 7)) << 3);
                ah[ko] = *reinterpret_cast<const short8*>(&xh[aidx]);
                al[ko] = *reinterpret_cast<const short8*>(&xl[aidx]);
            }
#pragma unroll
            for (int ct = 0; ct < 4; ++ct) {
                const int brow = ct * 16 + lr;
#pragma unroll
                for (int ko = 0; ko < 2; ++ko) {
                    int bidx = brow * 64 + (((ko * 4 + lg) ^ (brow & 7)) << 3);
                    short8 bh = *reinterpret_cast<const short8*>(&wh[bidx]);
                    short8 bl = *reinterpret_cast<const short8*>(&wl[bidx]);
                    acc[ct] = MFMA16(ah[ko], bh, acc[ct]);
                    acc[ct] = MFMA16(ah[ko], bl, acc[ct]);
                    acc[ct] = MFMA16(al[ko], bh, acc[ct]);
                }
            }
        }
        __syncthreads();
    }
    const int rbase = mb + wid * 16 + lg * 4;
#pragma unroll
    for (int ct = 0; ct < 4; ++ct) {
        int col = nb + ct * 16 + lr;
        if (w == 2) {   // V stored transposed
            ushort4 v4;
            v4.x = f2bf(acc[ct][0]); v4.y = f2bf(acc[ct][1]);
            v4.z = f2bf(acc[ct][2]); v4.w = f2bf(acc[ct][3]);
            *reinterpret_cast<ushort4*>(VT + (size_t)col * 8192 + rbase) = v4;
        } else {
            unsigned short* Hi = (w == 0) ? Qhi : Khi;
            unsigned short* Lo = (w == 0) ? Qlo : Klo;
            const float scale = (w == 0) ? 16.0f : 1.0f;
#pragma unroll
            for (int j = 0; j < 4; ++j) {
                float v = acc[ct][j] * scale;
                unsigned short h = f2bf(v);
                unsigned short lo = f2bf(v - bf2f(h));
                Hi[(size_t)(rbase + j) * 256 + col] = h;
                Lo[(size_t)(rbase + j) * 256 + col] = lo;
            }
        }
    }
}

// ---------------- kernel 3: flash attention (swapped QK^T) ----------------
// BM=64 (4 waves x 16 rows), KVBLK=32, KV-split=4, 512 blocks = 2/CU lockstep.
// S^T = K*Q^T so each lane owns one q-row; softmax nearly shuffle-free;
// P transposed in-register (cvt_pk + xor16/xor48 butterfly); O^T accumulator.
__launch_bounds__(256, 2)
__global__ void flash_kernel(const unsigned short* __restrict__ Qhi,
                             const unsigned short* __restrict__ Qlo,
                             const unsigned short* __restrict__ Khi_g,
                             const unsigned short* __restrict__ Klo_g,
                             const unsigned short* __restrict__ VT,
                             unsigned short* __restrict__ Opart,
                             float* __restrict__ Mpart, float* __restrict__ Lpart) {
    __shared__ __align__(16) unsigned short Kh[32 * 256], Kl[32 * 256];
    __shared__ __align__(16) unsigned short Vt[256 * 32];
    const int t = threadIdx.x;
    const int bid = blockIdx.x;
    const int work = (bid & 7) * 64 + (bid >> 3);   // chunked XCD mapping
    const int split = work >> 7, mtile = work & 127;
    const int mb = mtile * 64;
    const int kv0 = split * 2048;
    const int wid = t >> 6, lane = t & 63, lr = lane & 15, lg = lane >> 4;

    // Q fragments (B-frag: col=q=lr, k=lg*8+j) — same per-lane data as before
    const int qrow = mb + wid * 16 + lr;
    short8 qh[8], ql[8];
#pragma unroll
    for (int ko = 0; ko < 8; ++ko) {
        int g = qrow * 256 + ko * 32 + lg * 8;
        qh[ko] = *reinterpret_cast<const short8*>(Qhi + g);
        ql[ko] = *reinterpret_cast<const short8*>(Qlo + g);
    }

    // staging offsets (pre-swizzled global src, linear LDS dest)
    int khoff[4], vtoff[4], kc[4];
#pragma unroll
    for (int i = 0; i < 4; ++i) {
        int c = wid * 4 + i;
        kc[i] = c * 512;
        int krow = c * 2 + (lane >> 5), ksl = lane & 31;
        khoff[i] = krow * 256 + ((ksl ^ (krow & 7)) << 3);
        int vrow = c * 16 + (lane >> 2), vl = lane & 3;
        vtoff[i] = vrow * 8192 + ((vl ^ (vrow & 3)) << 3);
    }

    const f32x4 fzero = {0.f, 0.f, 0.f, 0.f};
    f32x4 acc[16];                               // O^T: d = dt*16+lg*4+j, q = lr
#pragma unroll
    for (int i = 0; i < 16; ++i) acc[i] = fzero;
    float m = -__builtin_inff(), lp = 0.f;       // per-lane (q = lr) partials
    const int xr7 = lr & 7, xr3 = lr & 3;
    const bool lgEven = (lg & 1) == 0;
    const bool lgMid = (lg == 1) || (lg == 2);

    for (int it = 0; it < 64; ++it) {
        const int kvb = kv0 + it * 32;
        const int kb = kvb << 8;
#pragma unroll
        for (int i = 0; i < 4; ++i) {
            gl16(Khi_g + kb + khoff[i], (unsigned short*)Kh + kc[i]);
            gl16(Klo_g + kb + khoff[i], (unsigned short*)Kl + kc[i]);
            gl16(VT + kvb + vtoff[i], (unsigned short*)Vt + kc[i]);
        }
        asm volatile("s_waitcnt vmcnt(0)" ::: "memory");
        __syncthreads();
        // ---- S^T = K Q^T : lane holds S[kv=lg*4+j (+16)][q=lr] ----
        f32x4 s0 = fzero, s1 = fzero;
        __builtin_amdgcn_s_setprio(1);
#pragma unroll
        for (int ko = 0; ko < 8; ++ko) {
            int sl = (((ko * 4 + lg) ^ xr7) << 3);
            int b0 = lr * 256 + sl;
            int b1 = b0 + 4096;
            short8 bh0 = *reinterpret_cast<const short8*>(&Kh[b0]);
            short8 bl0 = *reinterpret_cast<const short8*>(&Kl[b0]);
            short8 bh1 = *reinterpret_cast<const short8*>(&Kh[b1]);
            short8 bl1 = *reinterpret_cast<const short8*>(&Kl[b1]);
            s0 = MFMA16(bh0, qh[ko], s0);
            s1 = MFMA16(bh1, qh[ko], s1);
            s0 = MFMA16(bl0, qh[ko], s0);
            s1 = MFMA16(bl1, qh[ko], s1);
            s0 = MFMA16(bh0, ql[ko], s0);
            s1 = MFMA16(bh1, ql[ko], s1);
        }
        __builtin_amdgcn_s_setprio(0);
        // ---- softmax: row-max = 7 in-lane max + 2 shfl ----
        float mx = fmaxf(fmaxf(fmaxf(s0[0], s0[1]), fmaxf(s0[2], s0[3])),
                         fmaxf(fmaxf(s1[0], s1[1]), fmaxf(s1[2], s1[3])));
        mx = fmaxf(mx, __shfl_xor(mx, 16));
        mx = fmaxf(mx, __shfl_xor(mx, 32));
        if (!__all(mx - m <= 4.0f)) {            // defer-max THR=4
            float nm = fmaxf(m, mx);
            float sc = __expf(m - nm);
            lp *= sc;
            m = nm;
#pragma unroll
            for (int i = 0; i < 16; ++i) acc[i] *= sc;
        }
        float p0[4], p1[4];
#pragma unroll
        for (int j = 0; j < 4; ++j) {
            p0[j] = __expf(s0[j] - m);           // bounded by e^4
            p1[j] = __expf(s1[j] - m);
        }
        lp += (p0[0] + p0[1]) + (p0[2] + p0[3]) + (p1[0] + p1[1]) + (p1[2] + p1[3]);
        // ---- in-register P transpose -> PV B-frag (kv pair t_n = kv/2) ----
        unsigned int A0 = cvtpk(p0[0], p0[1]);   // t = 2lg
        unsigned int A1 = cvtpk(p0[2], p0[3]);   // t = 2lg+1
        unsigned int B0 = cvtpk(p1[0], p1[1]);   // t = 8+2lg
        unsigned int B1 = cvtpk(p1[2], p1[3]);   // t = 8+2lg+1
        unsigned int X0 = __shfl_xor(A0, 16), X1 = __shfl_xor(A1, 16);
        unsigned int Y0 = __shfl_xor(B0, 16), Y1 = __shfl_xor(B1, 16);
        unsigned int U0 = lgEven ? A0 : Y0, U1 = lgEven ? A1 : Y1;
        unsigned int U2 = lgEven ? X0 : B0, U3 = lgEven ? X1 : B1;
        unsigned int V0 = __shfl_xor(U0, 48), V1 = __shfl_xor(U1, 48);
        unsigned int V2 = __shfl_xor(U2, 48), V3 = __shfl_xor(U3, 48);
        u32x4 wv;
        wv[0] = lgMid ? V0 : U0; wv[1] = lgMid ? V1 : U1;
        wv[2] = lgMid ? V2 : U2; wv[3] = lgMid ? V3 : U3;
        short8 pa = __builtin_bit_cast(short8, wv);   // P^T[kv=lg*8+j][q=lr]
        // ---- O^T += V^T P^T ----
        __builtin_amdgcn_s_setprio(1);
#pragma unroll
        for (int dt = 0; dt < 16; ++dt) {
            int vidx = (dt * 16 + lr) * 32 + ((lg ^ xr3) << 3);
            short8 bv = *reinterpret_cast<const short8*>(&Vt[vidx]);
            acc[dt] = MFMA16(bv, pa, acc[dt]);
        }
        __builtin_amdgcn_s_setprio(0);
        __syncthreads();
    }
    // ---- epilogue: reduce lp across lg; store bf16 O (row-major) + (m, l) ----
    lp += __shfl_xor(lp, 16);
    lp += __shfl_xor(lp, 32);
    const int orow = mb + wid * 16 + lr;
    unsigned short* Ob = Opart + (size_t)split * 8192 * 256 + (size_t)orow * 256 + lg * 4;
#pragma unroll
    for (int dt = 0; dt < 16; ++dt) {
        unsigned int k0 = cvtpk(acc[dt][0], acc[dt][1]);
        unsigned int k1 = cvtpk(acc[dt][2], acc[dt][3]);
        *reinterpret_cast<unsigned int*>(Ob + dt * 16) = k0;
        *reinterpret_cast<unsigned int*>(Ob + dt * 16 + 2) = k1;
    }
    if (lg == 0) {
        Mpart[split * 8192 + orow] = m;
        Lpart[split * 8192 + orow] = lp;
    }
}

// ---------------- kernel 4: combine 4 KV-split partials ----------------
__global__ void combine_kernel(const unsigned short* __restrict__ Opart,
                               const float* __restrict__ Mpart,
                               const float* __restrict__ Lpart,
                               float* __restrict__ out) {
    const int row = blockIdx.x;
    const int d = threadIdx.x;
    float mm = -__builtin_inff();
#pragma unroll
    for (int s = 0; s < 4; ++s) mm = fmaxf(mm, Mpart[s * 8192 + row]);
    float num = 0.f, den = 0.f;
#pragma unroll
    for (int s = 0; s < 4; ++s) {
        float w = __expf(Mpart[s * 8192 + row] - mm);
        den += w * Lpart[s * 8192 + row];
        num += w * bf2f(Opart[((size_t)s * 8192 + row) * 256 + d]);
    }
    out[(size_t)row * 256 + d] = num / den;
}

extern "C" void kernel_launch(void* const* d_in, const int* in_sizes, int n_in,
                              void* d_out, int out_size, void* d_ws, size_t ws_size,
                              hipStream_t stream) {
    const float* x  = (const float*)d_in[0];
    const float* Wq = (const float*)d_in[1];
    const float* Wk = (const float*)d_in[2];
    const float* Wv = (const float*)d_in[3];
    float* out = (float*)d_out;

    char* ws = (char*)d_ws;
    const size_t SZ_QK = (size_t)8192 * 256 * 2;     // 4 MiB per bf16 array
    unsigned short* Qhi = (unsigned short*)(ws + 0 * SZ_QK);
    unsigned short* Qlo = (unsigned short*)(ws + 1 * SZ_QK);
    unsigned short* Khi = (unsigned short*)(ws + 2 * SZ_QK);
    unsigned short* Klo = (unsigned short*)(ws + 3 * SZ_QK);
    unsigned short* VT  = (unsigned short*)(ws + 4 * SZ_QK);
    float* Mpart = (float*)(ws + 5 * SZ_QK);                    // 128KB
    float* Lpart = (float*)(ws + 5 * SZ_QK + 131072);           // 128KB
    char* uA = ws + 5 * SZ_QK + 262144;              // union region:
    unsigned short* xhi = (unsigned short*)uA;       //   A: xhi+xlo (32MB) + Whi/Wlo (3MB)
    unsigned short* xlo = (unsigned short*)(uA + (size_t)8192 * 1024 * 2);
    unsigned short* Whi = (unsigned short*)(uA + (size_t)2 * 8192 * 1024 * 2);
    unsigned short* Wlo = (unsigned short*)(uA + (size_t)2 * 8192 * 1024 * 2 + 3 * 262144 * 2);
    unsigned short* Opart = (unsigned short*)uA;     //   B: Opart bf16 (16MB)

    convert_x_kernel<<<8192, 256, 0, stream>>>(x, xhi, xlo);
    convert_w_kernel<<<dim3(256, 3), 256, 0, stream>>>(Wq, Wk, Wv, Whi, Wlo);
    proj_kernel<<<dim3(128, 12), 256, 0, stream>>>(xhi, xlo, Whi, Wlo,
                                                   Qhi, Qlo, Khi, Klo, VT);
    flash_kernel<<<512, 256, 0, stream>>>(Qhi, Qlo, Khi, Klo, VT, Opart, Mpart, Lpart);
    combine_kernel<<<8192, 256, 0, stream>>>(Opart, Mpart, Lpart, out);
}